// Round 18
// baseline (96.925 us; speedup 1.0000x reference)
//
#include <hip/hip_runtime.h>
#include <cstddef>

using bf16x8  = __attribute__((ext_vector_type(8))) short;
using short4v = __attribute__((ext_vector_type(4))) short;
using f32x4   = __attribute__((ext_vector_type(4))) float;
using ushort8 = __attribute__((ext_vector_type(8))) unsigned short;

#define GLL16(gp, lp) __builtin_amdgcn_global_load_lds( \
    (const __attribute__((address_space(1))) unsigned int*)(const void*)(gp), \
    (__attribute__((address_space(3))) unsigned int*)(void*)(lp), 16, 0, 0)

__device__ __forceinline__ float exp2_f(float x){ float r; asm("v_exp_f32 %0, %1" : "=v"(r) : "v"(x)); return r; }
__device__ __forceinline__ float rcp_f (float x){ float r; asm("v_rcp_f32 %0, %1" : "=v"(r) : "v"(x)); return r; }
__device__ __forceinline__ unsigned pk2(float lo, float hi){
  unsigned r; asm("v_cvt_pk_bf16_f32 %0, %1, %2" : "=v"(r) : "v"(lo), "v"(hi)); return r;
}
__device__ __forceinline__ unsigned short f2bf(float f){
  unsigned int u = __float_as_uint(f);
  u = u + 0x7FFFu + ((u >> 16) & 1u);
  return (unsigned short)(u >> 16);
}
__device__ __forceinline__ float bf2f(unsigned short s){
  return __uint_as_float(((unsigned int)s) << 16);
}

// 4-way merged reciprocal sum: a += sum_i vv_i/(1+ek_i*eq_i), ONE rcp per 4.
#define QUAD(E, k0v,k1v,k2v,k3v, w0v,w1v,w2v,w3v, a) { \
  const float d0 = fmaf((k0v), (E).x, 1.f); \
  const float d1 = fmaf((k1v), (E).y, 1.f); \
  const float d2 = fmaf((k2v), (E).z, 1.f); \
  const float d3 = fmaf((k3v), (E).w, 1.f); \
  const float p01 = d0 * d1, p23 = d2 * d3; \
  const float n01 = fmaf((w1v), d0, (w0v) * d1); \
  const float n23 = fmaf((w3v), d2, (w2v) * d3); \
  (a) = fmaf(fmaf(n01, p23, n23 * p01), rcp_f(p01 * p23), (a)); }

// problem sizes: B=8 Q=16 KV=2048 NQ=NK=NV=H=512
#define QG_BLOCKS 16              // qgemm blocks (reads query/W f32 directly)
#define WK_BLOCKS 128             // wk f32->bf16 convert
#define SCALE_2LOG2E 2.885390081777927f   // 2*log2(e): exp2(x*S) = exp(2x)

// workspace layout (bytes); total = 10,223,616
#define OFF_WK_BF     0u          // 512x512 bf16
#define OFF_EQB       524288u     // 128x512 f32: exp2(S*q_part)
#define OFF_EPART     786432u     // 8 x [8*2048*16] f32 partial logits
#define OFF_SC        9175040u    // 8x2048x16 f32 scores

// ---------------- K1: q-GEMM (blocks 0..15) ∥ wk convert (16..143) --------
__global__ __launch_bounds__(256) void k_convert(
    const float* __restrict__ W, const float* __restrict__ query,
    unsigned short* __restrict__ wk_bf, float* __restrict__ eqb)
{
  __shared__ short qg[128*32 + 32*32];     // 10 KB (qgemm branch only)
  if (blockIdx.x < QG_BLOCKS) {
    const int n0 = blockIdx.x * 32;
    const int tid = threadIdx.x;
    const int l = tid & 63, w = tid >> 6;
    short* A  = qg;                 // [128][32] swizzled
    short* Bs = qg + 4096;          // [32][32] swizzled
    const int sub = tid >> 3;       // 0..31
    const int c4  = (tid & 7) * 4;  // col within 32
    const int wm = w & 1, wn = w >> 1;
    const int fr = l & 15, fg = l >> 4;

    f32x4 acc[4];
    #pragma unroll
    for (int i = 0; i < 4; ++i) acc[i] = (f32x4){0.f,0.f,0.f,0.f};

    float4 a4[4], b4, a4n[4], b4n;
    #pragma unroll
    for (int m = 0; m < 4; ++m)
      a4[m] = *(const float4*)(query + (size_t)(m * 32 + sub) * 512 + c4);
    b4 = *(const float4*)(W + (size_t)(n0 + sub) * 1024 + c4);

    for (int kt = 0; kt < 16; ++kt) {
      if (kt < 15) {
        const int k0 = (kt + 1) * 32;
        #pragma unroll
        for (int m = 0; m < 4; ++m)
          a4n[m] = *(const float4*)(query + (size_t)(m * 32 + sub) * 512 + k0 + c4);
        b4n = *(const float4*)(W + (size_t)(n0 + sub) * 1024 + k0 + c4);
      }
      __syncthreads();
      #pragma unroll
      for (int m = 0; m < 4; ++m) {
        const int row = m * 32 + sub;
        const int o = row * 32 + (((c4 >> 3) ^ ((row >> 1) & 3)) << 3) + (c4 & 7);
        *(uint2*)&A[o] = make_uint2(pk2(a4[m].x, a4[m].y), pk2(a4[m].z, a4[m].w));
      }
      {
        const int o = sub * 32 + (((c4 >> 3) ^ ((sub >> 1) & 3)) << 3) + (c4 & 7);
        *(uint2*)&Bs[o] = make_uint2(pk2(b4.x, b4.y), pk2(b4.z, b4.w));
      }
      __syncthreads();
      bf16x8 af[4], bfv;
      #pragma unroll
      for (int i = 0; i < 4; ++i) {
        const int ar = wm*64 + i*16 + fr;
        af[i] = *(const bf16x8*)&A[ar*32 + ((fg ^ ((ar>>1)&3)) << 3)];
      }
      const int br = wn*16 + fr;
      bfv = *(const bf16x8*)&Bs[br*32 + ((fg ^ ((br>>1)&3)) << 3)];
      #pragma unroll
      for (int i = 0; i < 4; ++i)
        acc[i] = __builtin_amdgcn_mfma_f32_16x16x32_bf16(af[i], bfv, acc[i], 0, 0, 0);
      if (kt < 15) {
        #pragma unroll
        for (int m = 0; m < 4; ++m) a4[m] = a4n[m];
        b4 = b4n;
      }
    }
    const int gh = n0 + wn*16 + fr;
    #pragma unroll
    for (int i = 0; i < 4; ++i)
      #pragma unroll
      for (int r = 0; r < 4; ++r) {
        const int gm = wm*64 + i*16 + fg*4 + r;
        eqb[gm * 512 + gh] = exp2_f(acc[i][r] * SCALE_2LOG2E);
      }
    return;
  }
  // ---- wk convert path: 128 blocks x 2048 elems
  int e = (blockIdx.x - QG_BLOCKS) * 2048 + threadIdx.x * 8;
  const float* src = W + (size_t)(e >> 9) * 1024 + 512 + (e & 511);
  float4 a = *(const float4*)src;
  float4 b = *(const float4*)(src + 4);
  ushort8 o;
  o[0]=f2bf(a.x); o[1]=f2bf(a.y); o[2]=f2bf(a.z); o[3]=f2bf(a.w);
  o[4]=f2bf(b.x); o[5]=f2bf(b.y); o[6]=f2bf(b.z); o[7]=f2bf(b.w);
  *(ushort8*)&wk_bf[e] = o;
}

// ---------------- K2: FUSED convert + k-GEMM + energy ---------------------
// Tile M=128 x N=64, grid (128 by, 8 hc) = 1024 blocks -> 4 blocks/CU.
// h-split (not row-split) keeps per-CU eqs/VALU work constant while doubling
// wave-slots (the r10 confound, fixed). LDS 36KB: A 16K (single, union ekbf
// 16K) + B dbuf 16K + eqs 4K. A: keys f32 reg-staged 1-kt-ahead; B: GLL16
// counted-vmcnt.
struct FusedSM {
  union {
    short A[8192];                     // 16 KB (128x64 bf16, swizzled)
    unsigned short ekbf[128 * 64];     // 16 KB
  } u;
  short B[2][4096];                    // 16 KB (2 x 64x64 bf16, swizzled)
  float eqs[16 * 64];                  // 4 KB
};

__global__ __launch_bounds__(256, 4) void k_fused(
    const float* __restrict__ keys, const unsigned short* __restrict__ wk_bf,
    const float* __restrict__ w_bias, const float* __restrict__ eqb,
    const float* __restrict__ vw, float* __restrict__ e_part)
{
  __shared__ FusedSM sm;
  const int tid = threadIdx.x;
  const int l = tid & 63, w = tid >> 6;
  const int by = blockIdx.x;              // 0..127 m-tile (128 k-rows)
  const int hc = blockIdx.y;              // 0..7 h-chunk (64 h)
  const int h0 = hc * 64;
  const int b  = by >> 4;

  const float* Akeys = keys + (size_t)by * 128 * 512;
  const unsigned short* Bptr = wk_bf + (size_t)h0 * 512;

  const int wm = w >> 1, wn = w & 1;
  const int fr = l & 15, fg = l >> 4;
  const int axk = fr & 7;

  f32x4 acc[4][2];
  #pragma unroll
  for (int i = 0; i < 4; ++i)
    #pragma unroll
    for (int j = 0; j < 2; ++j) acc[i][j] = (f32x4){0.f,0.f,0.f,0.f};

  float4 areg[8];
  auto aload = [&](int kt) {          // 8 float4 coalesced loads (128x64 f32)
    const float* src = Akeys + kt * 64;
    #pragma unroll
    for (int m = 0; m < 8; ++m) {
      const int u = m * 256 + tid;
      areg[m] = *(const float4*)(src + (size_t)(u >> 4) * 512 + (u & 15) * 4);
    }
  };
  auto awrite = [&]() {               // cvt_pk + swizzled ds_write_b64
    #pragma unroll
    for (int m = 0; m < 8; ++m) {
      const int u = m * 256 + tid;
      const int row = u >> 4, c4 = u & 15;
      const int o = row * 64 + (((c4 >> 1) ^ (row & 7)) << 3) + (c4 & 1) * 4;
      *(uint2*)&sm.u.A[o] =
          make_uint2(pk2(areg[m].x, areg[m].y), pk2(areg[m].z, areg[m].w));
    }
  };
  auto bstage = [&](int buf, int kt) { // 2 GLL16 (64x64 bf16), pre-swizzled src
    const int k0 = kt * 64;
    #pragma unroll
    for (int m = 0; m < 2; ++m) {
      const int u = m * 256 + tid;                 // 16B unit
      const int row = u >> 3, chunk = u & 7;
      GLL16(Bptr + (size_t)row * 512 + k0 + ((chunk ^ (row & 7)) << 3),
            &sm.B[buf][(m * 256 + (w << 6)) * 8 + 0] + (l << 3));
    }
  };
  auto compute = [&](int buf) {
    #pragma unroll
    for (int ks = 0; ks < 2; ++ks) {
      bf16x8 af[4], bfv[2];
      #pragma unroll
      for (int i = 0; i < 4; ++i) {
        const int ar = wm*64 + i*16 + fr;
        af[i] = *(const bf16x8*)&sm.u.A[ar*64 + ((ks*4 + fg) ^ axk) * 8];
      }
      #pragma unroll
      for (int j = 0; j < 2; ++j) {
        const int br = wn*32 + j*16 + fr;
        bfv[j] = *(const bf16x8*)&sm.B[buf][br*64 + ((ks*4 + fg) ^ axk) * 8];
      }
      #pragma unroll
      for (int i = 0; i < 4; ++i)
        #pragma unroll
        for (int j = 0; j < 2; ++j)
          acc[i][j] = __builtin_amdgcn_mfma_f32_16x16x32_bf16(af[i], bfv[j], acc[i][j], 0, 0, 0);
    }
  };

  // prologue: eqs + tile0 A staged; B(0) + A(1) in flight
  aload(0);
  {
    const int q = tid >> 4, c0 = (tid & 15) * 4;
    const float4 e4 = *(const float4*)(eqb + (size_t)(b * 16 + q) * 512 + h0 + c0);
    asm volatile("s_waitcnt vmcnt(0)" ::: "memory");
    *(float4*)&sm.eqs[q * 64 + c0] = e4;
  }
  awrite();
  bstage(0, 0);
  aload(1);
  asm volatile("s_waitcnt lgkmcnt(0)" ::: "memory");

  #pragma unroll 1
  for (int kt = 0; kt < 8; ++kt) {
    if (kt < 7) asm volatile("s_waitcnt vmcnt(8)" ::: "memory");  // B(kt) landed
    else        asm volatile("s_waitcnt vmcnt(0)" ::: "memory");
    __builtin_amdgcn_sched_barrier(0);
    __builtin_amdgcn_s_barrier();      // A(kt) + B(kt) staged for all waves
    __builtin_amdgcn_sched_barrier(0);
    compute(kt & 1);
    asm volatile("s_waitcnt lgkmcnt(0)" ::: "memory");
    __builtin_amdgcn_sched_barrier(0);
    __builtin_amdgcn_s_barrier();      // all reads of A + B(kt&1) done
    __builtin_amdgcn_sched_barrier(0);
    if (kt < 7) {
      asm volatile("s_waitcnt vmcnt(0)" ::: "memory");  // areg(kt+1) landed
      awrite();                                          // overwrite A (readers done)
      bstage((kt + 1) & 1, kt + 1);                      // 2 GLL16 in flight
      if (kt < 6) aload(kt + 2);                         // 8 loads in flight
      asm volatile("s_waitcnt lgkmcnt(0)" ::: "memory"); // awrite visible
      __builtin_amdgcn_sched_barrier(0);
    }
  }

  // acc -> ekbf (bf16) in A region (dead); swizzle chunk' = chunk ^ (row&7)
  #pragma unroll
  for (int j = 0; j < 2; ++j) {
    const int col = wn*32 + j*16 + fr;
    const float bias = w_bias[h0 + col];
    const int chunk = col >> 3, coff = col & 7;
    #pragma unroll
    for (int i = 0; i < 4; ++i)
      #pragma unroll
      for (int r = 0; r < 4; ++r) {
        const int row = wm*64 + i*16 + fg*4 + r;
        const float ev = exp2_f((acc[i][j][r] + bias) * SCALE_2LOG2E);
        sm.u.ekbf[row * 64 + ((chunk ^ ((fg*4 + r) & 7)) << 3) + coff] = f2bf(ev);
      }
  }
  // v weights (pre-scaled by -2); lane owns h {s*32 + hf*16 + g*4 + u}
  const int g = l & 3, kl = l >> 2;
  float vv[16];
  #pragma unroll
  for (int s = 0; s < 2; ++s)
    #pragma unroll
    for (int hf = 0; hf < 2; ++hf) {
      const float4 a4 = *(const float4*)(vw + h0 + s*32 + hf*16 + g*4);
      const int o = s*8 + hf*4;
      vv[o+0]=-2.f*a4.x; vv[o+1]=-2.f*a4.y; vv[o+2]=-2.f*a4.z; vv[o+3]=-2.f*a4.w;
    }
  __syncthreads();

  // energy: wave w owns rows {w*32+kl, w*32+16+kl}; QUAD: 1 rcp per 4 terms
  {
    const int lr0 = w * 32 + kl;                 // lr0&7 = kl&7
    const int lr1 = lr0 + 16;                    // same &7 -> same ck
    float ek0[16], ek1[16];
    #pragma unroll
    for (int s = 0; s < 2; ++s)
      #pragma unroll
      for (int hf = 0; hf < 2; ++hf) {
        const int ck = (s*4 + hf*2 + (g >> 1)) ^ (kl & 7);
        const short4v v40 = *(const short4v*)&sm.u.ekbf[lr0 * 64 + (ck << 3) + (g & 1) * 4];
        const short4v v41 = *(const short4v*)&sm.u.ekbf[lr1 * 64 + (ck << 3) + (g & 1) * 4];
        #pragma unroll
        for (int u = 0; u < 4; ++u) {
          ek0[s*8 + hf*4 + u] = bf2f((unsigned short)v40[u]);
          ek1[s*8 + hf*4 + u] = bf2f((unsigned short)v41[u]);
        }
      }
    const size_t ep0 = (size_t)hc * 262144 + ((size_t)(by * 128 + lr0)) * 16;
    const size_t ep1 = (size_t)hc * 262144 + ((size_t)(by * 128 + lr1)) * 16;
    #pragma unroll 4
    for (int q = 0; q < 16; ++q) {
      float a00 = 0.f, a01 = 0.f, a10 = 0.f, a11 = 0.f;
      #pragma unroll
      for (int s = 0; s < 2; ++s) {
        const float* er = &sm.eqs[q * 64 + s * 32 + g * 4];
        const float4 E0 = *(const float4*)er;
        const float4 E1 = *(const float4*)(er + 16);
        QUAD(E0, ek0[s*8+0],ek0[s*8+1],ek0[s*8+2],ek0[s*8+3],
                 vv[s*8+0],vv[s*8+1],vv[s*8+2],vv[s*8+3], a00);
        QUAD(E1, ek0[s*8+4],ek0[s*8+5],ek0[s*8+6],ek0[s*8+7],
                 vv[s*8+4],vv[s*8+5],vv[s*8+6],vv[s*8+7], a01);
        QUAD(E0, ek1[s*8+0],ek1[s*8+1],ek1[s*8+2],ek1[s*8+3],
                 vv[s*8+0],vv[s*8+1],vv[s*8+2],vv[s*8+3], a10);
        QUAD(E1, ek1[s*8+4],ek1[s*8+5],ek1[s*8+6],ek1[s*8+7],
                 vv[s*8+4],vv[s*8+5],vv[s*8+6],vv[s*8+7], a11);
      }
      float r0 = a00 + a01;
      r0 += __shfl_xor(r0, 1, 64);
      r0 += __shfl_xor(r0, 2, 64);
      float r1 = a10 + a11;
      r1 += __shfl_xor(r1, 1, 64);
      r1 += __shfl_xor(r1, 2, 64);
      if (g == 0) { e_part[ep0 + q] = r0; e_part[ep1 + q] = r1; }
    }
  }
}

// ---------------- K3: softmax over k: sum 8 partials, normalize -----------
__global__ __launch_bounds__(256) void k_softmax(
    const float* __restrict__ e_part, float* __restrict__ sc)
{
  const int b = blockIdx.x >> 4, q = blockIdx.x & 15;
  const int base = b * 32768 + q;           // stride 16 over k
  const int tid = threadIdx.x;
  __shared__ float redm[4], reds[4];

  float vals[8];
  float mx = -1e30f;
  #pragma unroll
  for (int i = 0; i < 8; ++i) {
    const int x = base + (tid + i * 256) * 16;
    float s = 0.f;
    #pragma unroll
    for (int p = 0; p < 8; ++p) s += e_part[x + p * 262144];
    vals[i] = s;
    mx = fmaxf(mx, vals[i]);
  }
  #pragma unroll
  for (int msk = 1; msk < 64; msk <<= 1) mx = fmaxf(mx, __shfl_xor(mx, msk, 64));
  if ((tid & 63) == 0) redm[tid >> 6] = mx;
  __syncthreads();
  mx = fmaxf(fmaxf(redm[0], redm[1]), fmaxf(redm[2], redm[3]));

  float ex[8], sum = 0.f;
  #pragma unroll
  for (int i = 0; i < 8; ++i) { ex[i] = __expf(vals[i] - mx); sum += ex[i]; }
  #pragma unroll
  for (int msk = 1; msk < 64; msk <<= 1) sum += __shfl_xor(sum, msk, 64);
  if ((tid & 63) == 0) reds[tid >> 6] = sum;
  __syncthreads();
  sum = reds[0] + reds[1] + reds[2] + reds[3];
  const float r = 1.f / sum;
  #pragma unroll
  for (int i = 0; i < 8; ++i) sc[base + (tid + i * 256) * 16] = ex[i] * r;
}

// ---------------- K4: single-pass PV -> out, 256 blocks x 512 thr ---------
__global__ __launch_bounds__(512) void k_pv(
    const float* __restrict__ values, const float* __restrict__ sc,
    float* __restrict__ out)
{
  __shared__ float lds[128 * 20];            // 10 KB (stride-20: 2-way max)
  const int tid = threadIdx.x;
  const int nc = blockIdx.x & 31, b = blockIdx.x >> 5;
  const int n = tid & 15, kg = tid >> 4;     // 32 kg x 16 n
  const int l = tid & 63, w = tid >> 6;      // 8 waves
  const int n0 = nc * 16;

  float acc[16];
  #pragma unroll
  for (int q = 0; q < 16; ++q) acc[q] = 0.f;

  for (int kc = 0; kc < 16; ++kc) {
    __syncthreads();
    {
      const float* ssrc = sc + (size_t)(b * 2048 + kc * 128) * 16;
      const int row = tid >> 2, c4 = (tid & 3) * 4;
      *(float4*)&lds[row * 20 + c4] = *(const float4*)&ssrc[row * 16 + c4];
    }
    __syncthreads();
    const float* vb = values + ((size_t)(b * 2048 + kc * 128 + kg * 4)) * 512 + n0 + n;
    #pragma unroll
    for (int k2 = 0; k2 < 4; ++k2) {
      const float v = vb[(size_t)k2 * 512];
      const float* sr = &lds[(kg * 4 + k2) * 20];
      #pragma unroll
      for (int qq = 0; qq < 4; ++qq) {
        const float4 s4 = *(const float4*)&sr[qq * 4];
        acc[qq*4+0] = fmaf(v, s4.x, acc[qq*4+0]);
        acc[qq*4+1] = fmaf(v, s4.y, acc[qq*4+1]);
        acc[qq*4+2] = fmaf(v, s4.z, acc[qq*4+2]);
        acc[qq*4+3] = fmaf(v, s4.w, acc[qq*4+3]);
      }
    }
  }
  // within-wave reduce (lanes l, l^16, l^32 share n)
  #pragma unroll
  for (int q = 0; q < 16; ++q) {
    acc[q] += __shfl_xor(acc[q], 16, 64);
    acc[q] += __shfl_xor(acc[q], 32, 64);
  }
  __syncthreads();
  if (l < 16) {
    #pragma unroll
    for (int q = 0; q < 16; ++q) lds[w * 256 + q * 16 + l] = acc[q];
  }
  __syncthreads();
  if (tid < 256) {
    const int q = tid >> 4, nn = tid & 15;
    float s = 0.f;
    #pragma unroll
    for (int w2 = 0; w2 < 8; ++w2) s += lds[w2 * 256 + q * 16 + nn];
    out[((size_t)(b * 16 + q)) * 512 + n0 + nn] = s;
  }
}

extern "C" void kernel_launch(void* const* d_in, const int* in_sizes, int n_in,
                              void* d_out, int out_size, void* d_ws, size_t ws_size,
                              hipStream_t stream)
{
  const float* query  = (const float*)d_in[0];
  const float* keys   = (const float*)d_in[1];
  const float* values = (const float*)d_in[2];
  const float* W      = (const float*)d_in[3];
  const float* w_bias = (const float*)d_in[4];
  const float* vw     = (const float*)d_in[5];
  // d_in[6] (v_bias) + sum_h v_h are (k)-constant logit shifts -> softmax-invariant.

  char* ws = (char*)d_ws;
  unsigned short* wk_bf = (unsigned short*)(ws + OFF_WK_BF);
  float* eqb    = (float*)(ws + OFF_EQB);
  float* e_part = (float*)(ws + OFF_EPART);
  float* sc     = (float*)(ws + OFF_SC);

  hipLaunchKernelGGL(k_convert, dim3(QG_BLOCKS + WK_BLOCKS), dim3(256), 0, stream,
                     W, query, wk_bf, eqb);
  hipLaunchKernelGGL(k_fused, dim3(128, 8), dim3(256), 0, stream,
                     keys, wk_bf, w_bias, eqb, vw, e_part);
  hipLaunchKernelGGL(k_softmax, dim3(128), dim3(256), 0, stream, e_part, sc);
  hipLaunchKernelGGL(k_pv, dim3(256), dim3(512), 0, stream, values, sc, (float*)d_out);
}